// Round 12
// baseline (140.693 us; speedup 1.0000x reference)
//
#include <hip/hip_runtime.h>
#include <stdint.h>

typedef __attribute__((ext_vector_type(8))) __bf16 bf16x8;
typedef __attribute__((ext_vector_type(4))) __bf16 bf16x4;
typedef __attribute__((ext_vector_type(4))) float f32x4;

// barrier WITHOUT vmcnt drain: LDS ops must land, global loads stay in flight
#define LGKM_BAR() do { asm volatile("s_waitcnt lgkmcnt(0)" ::: "memory"); \
                        __builtin_amdgcn_s_barrier(); } while (0)

namespace {
constexpr int N_ = 64, C_ = 512, P_ = 900, K_ = 64;
constexpr int PP = 960;                               // padded P
constexpr int XROW = 962;                             // Xa row stride (odd-dword)
constexpr size_t TOT_X = (size_t)N_ * C_ * P_;
constexpr size_t AT_BYTES = (size_t)N_ * K_ * PP * 2;          // bf16 a' [n][k][960]
constexpr size_t ASUM_OFF = AT_BYTES;                          // f32 [n][k]
constexpr size_t WBR_OFF  = ASUM_OFF + (size_t)N_ * K_ * 4;    // bf16 wbr [oct][k][8]
constexpr size_t SSQ_OFF  = WBR_OFF + (size_t)K_ * C_ * 2;     // f32 ssqq [4][n][960]
constexpr size_t LQ_OFF   = SSQ_OFF + (size_t)4 * N_ * PP * 4; // bf16 Lq [4][n][k][960]
}

// --- prep: wbr[oct][k][j] = bf16(w[k][oct*8+j]); zero asum.
__global__ __launch_bounds__(256) void k_prep_w(const float* __restrict__ w,
                                                __bf16* __restrict__ wbr,
                                                float* __restrict__ asum) {
  const int T = blockIdx.x * 256 + threadIdx.x;      // 0..4095
  const int k = T >> 6, oct = T & 63;
  const float4 a = *reinterpret_cast<const float4*>(w + (size_t)k * C_ + oct * 8);
  const float4 b = *reinterpret_cast<const float4*>(w + (size_t)k * C_ + oct * 8 + 4);
  bf16x8 o = { (__bf16)a.x, (__bf16)a.y, (__bf16)a.z, (__bf16)a.w,
               (__bf16)b.x, (__bf16)b.y, (__bf16)b.z, (__bf16)b.w };
  *reinterpret_cast<bf16x8*>(wbr + ((size_t)oct * K_ + k) * 8) = o;
  asum[T] = 0.f;
}

// --- phase 1 (split-K over c): block (n, c-quarter q) STREAMS its contiguous
//     460 KB x-slab sequentially; partial logits -> Lq bf16; partial ssq -> ssqq.
//     4 steps of 32 c; 8 waves = 2 k-half x 4 p-quarter; 15-f4 register ring.
__global__ __launch_bounds__(512) void k_phase1(const float* __restrict__ x,
                                                const __bf16* __restrict__ wbr,
                                                __bf16* __restrict__ Lq,
                                                float* __restrict__ ssqq) {
  __shared__ __bf16 Xa[2][32][XROW];   // 123 KB
  __shared__ bf16x8 Wl[1024];          // 16 KB: c-quarter of w, [oct16][k64]
  const int bid = blockIdx.x;
  const int n = bid >> 2, q = bid & 3;
  const int tid = threadIdx.x;
  const int w = tid >> 6, l = tid & 63;
  const int l15 = l & 15, lh = l >> 4;
  const int wk = w >> 2, wp = w & 3;   // k-half (32k), p-quarter (240p)

  {  // stage W quarter (octets q*16..q*16+16)
    const bf16x8* wq = reinterpret_cast<const bf16x8*>(wbr) + (size_t)q * 1024;
    bf16x8 t0 = wq[tid], t1 = wq[512 + tid];
    Wl[tid] = t0; Wl[512 + tid] = t1;
  }
  // zero pad cols [900, 962) once (both buffers)
  for (int idx = tid; idx < 2 * 32 * 62; idx += 512) {
    const int b = idx / 1984, r = idx - b * 1984;
    Xa[b][r / 62][900 + r % 62] = (__bf16)0.f;
  }

  const float* xbase = x + ((size_t)n * C_ + q * 128) * P_;   // 128 contiguous rows
  float4 ring[15];
  const bool stg = tid < 480;          // 480 thr x 15 f4 = 7200 f4 = 32 rows

  auto LOADS = [&](int s) {
    if (stg) {
      #pragma unroll
      for (int i = 0; i < 15; ++i)
        ring[i] = *reinterpret_cast<const float4*>(
            xbase + (size_t)s * 28800 + (size_t)(tid + i * 480) * 4);
    }
  };
  auto STORES = [&](int buf) {
    if (stg) {
      #pragma unroll
      for (int i = 0; i < 15; ++i) {
        const int fo = tid + i * 480;                 // f4 index; rows of 225 f4
        const int c = fo / 225, pq4 = (fo - c * 225) * 4;
        const float4 v = ring[i];
        bf16x4 o = { (__bf16)v.x, (__bf16)v.y, (__bf16)v.z, (__bf16)v.w };
        *reinterpret_cast<bf16x4*>(&Xa[buf][c][pq4]) = o;
      }
    }
  };

  LOADS(0); STORES(0);
  LGKM_BAR();

  f32x4 acc[15][2] = {};               // [p-tile][k-frag]
  float sq0 = 0.f, sq1 = 0.f;
  const int p1c = 512 + tid;           // second owned ssq column

  #pragma unroll
  for (int s = 0; s < 4; ++s) {
    if (s < 3) LOADS(s + 1);
    const int buf = s & 1;
    #pragma unroll
    for (int t = 0; t < 15; ++t) {
      const int p = wp * 240 + t * 16 + l15;
      bf16x8 b;
      #pragma unroll
      for (int j = 0; j < 8; ++j) b[j] = Xa[buf][lh * 8 + j][p];
      #pragma unroll
      for (int m = 0; m < 2; ++m) {
        bf16x8 a = Wl[(s * 4 + lh) * 64 + wk * 32 + m * 16 + l15];
        acc[t][m] = __builtin_amdgcn_mfma_f32_16x16x32_bf16(a, b, acc[t][m], 0, 0, 0);
      }
    }
    // ssq sweep over this 32-c chunk (each thread owns cols tid and 512+tid)
    #pragma unroll
    for (int cc = 0; cc < 32; ++cc) {
      const float v0 = (float)Xa[buf][cc][tid];
      sq0 = fmaf(v0, v0, sq0);
      if (p1c < PP) { const float v1 = (float)Xa[buf][cc][p1c]; sq1 = fmaf(v1, v1, sq1); }
    }
    if (s < 3) { STORES((s + 1) & 1); LGKM_BAR(); }
  }

  // partial ssq out (direct stores, per-thread-owned columns)
  float* sqo = ssqq + ((size_t)q * N_ + n) * PP;
  sqo[tid] = sq0;
  if (p1c < PP) sqo[p1c] = sq1;

  // partial logits out (bf16), block-contiguous region
  __bf16* lqo = Lq + ((size_t)q * N_ + n) * K_ * PP;
  #pragma unroll
  for (int t = 0; t < 15; ++t) {
    const int p = wp * 240 + t * 16 + l15;
    #pragma unroll
    for (int m = 0; m < 2; ++m)
      #pragma unroll
      for (int r = 0; r < 4; ++r) {
        const int k = wk * 32 + m * 16 + lh * 4 + r;
        lqo[(size_t)k * PP + p] = (__bf16)acc[t][m][r];
      }
  }
}

// --- softmax: sum 4 partials (L3-hot), maxless softmax, write a' + asum.
//     Block (p-tile 64, n); 256 thr = 64 k x 4 p-groups of 16.
__global__ __launch_bounds__(256) void k_softmax(const __bf16* __restrict__ Lq,
                                                 const float* __restrict__ ssqq,
                                                 __bf16* __restrict__ at,
                                                 float* __restrict__ asum) {
  __shared__ float invn_l[64], invs_l[64], S_l[64], ak_l[64];
  __shared__ float Ls[64][66];
  const int n = blockIdx.y, pt = blockIdx.x;
  const int t = threadIdx.x;
  const int k = t & 63, pg = t >> 6;

  if (t < 64) {
    float ss = 0.f;
    #pragma unroll
    for (int q2 = 0; q2 < 4; ++q2)
      ss += ssqq[((size_t)q2 * N_ + n) * PP + pt * 64 + t];
    invn_l[t] = 1.f / fmaxf(sqrtf(ss), 1e-12f);
    S_l[t] = 0.f; ak_l[t] = 0.f;
  }
  __syncthreads();

  float L[16];
  #pragma unroll
  for (int i = 0; i < 16; ++i) L[i] = 0.f;
  const size_t QS = (size_t)N_ * K_ * PP;
  const __bf16* lb = Lq + ((size_t)n * K_ + k) * PP + pt * 64 + pg * 16;
  #pragma unroll
  for (int q2 = 0; q2 < 4; ++q2) {
    bf16x8 u0 = *reinterpret_cast<const bf16x8*>(lb + q2 * QS);
    bf16x8 u1 = *reinterpret_cast<const bf16x8*>(lb + q2 * QS + 8);
    #pragma unroll
    for (int i = 0; i < 8; ++i) { L[i] += (float)u0[i]; L[8 + i] += (float)u1[i]; }
  }
  float e[16];
  #pragma unroll
  for (int i = 0; i < 16; ++i) {
    const int p = pt * 64 + pg * 16 + i;
    e[i] = (p < P_) ? __expf(L[i] * invn_l[pg * 16 + i]) : 0.f;  // maxless: |logit|<=~0.5
    Ls[k][pg * 16 + i] = e[i];
  }
  __syncthreads();
  {
    const int pl = t & 63, kc = t >> 6;
    float s = 0.f;
    #pragma unroll
    for (int kk = 0; kk < 16; ++kk) s += Ls[kc * 16 + kk][pl];
    atomicAdd(&S_l[pl], s);
  }
  __syncthreads();
  if (t < 64) {
    const float S = S_l[t];
    invs_l[t] = (S > 0.f) ? 1.f / S : 0.f;
  }
  __syncthreads();

  float aps = 0.f;
  bf16x8 o0, o1;
  #pragma unroll
  for (int i = 0; i < 16; ++i) {
    const float a = e[i] * invs_l[pg * 16 + i];
    aps += a;
    const float ap = a * invn_l[pg * 16 + i];
    if (i < 8) o0[i] = (__bf16)ap; else o1[i - 8] = (__bf16)ap;
  }
  __bf16* ao = at + ((size_t)n * K_ + k) * PP + pt * 64 + pg * 16;
  *reinterpret_cast<bf16x8*>(ao)     = o0;
  *reinterpret_cast<bf16x8*>(ao + 8) = o1;
  atomicAdd(&ak_l[k], aps);
  __syncthreads();
  if (t < 64) unsafeAtomicAdd(asum + n * K_ + t, ak_l[t]);
}

// --- phase 2 (unchanged): vlad[k][c] = sum_p a'[k][p]*x[c][p] - asum[k]*cent[k][c]
__global__ __launch_bounds__(256) void k_phase2(const float* __restrict__ x,
                                                const __bf16* __restrict__ at,
                                                const float* __restrict__ asum,
                                                const float* __restrict__ cent,
                                                float* __restrict__ out) {
  __shared__ __bf16 Al[2][64][40];
  __shared__ __bf16 Xl[2][64][40];
  const int n   = blockIdx.y;
  const int c0  = blockIdx.x * 64;
  const int tid = threadIdx.x;
  const int w   = tid >> 6, l = tid & 63;
  const int l15 = l & 15,  lh = l >> 4;

  const int ak  = tid >> 2, ach = tid & 3;
  const int xc  = tid >> 3, xch = tid & 7;
  const size_t abase  = ((size_t)n * K_ + ak) * PP + ach * 8;
  const size_t xbase0 = ((size_t)n * C_ + c0 + xc) * P_ + xch * 4;
  const size_t xbase1 = ((size_t)n * C_ + c0 + xc + 32) * P_ + xch * 4;

  f32x4 acc[4] = {};
  bf16x8 na; float4 v0, v1;

  auto LOAD = [&](int s) {
    na = *reinterpret_cast<const bf16x8*>(at + abase + s * 32);
    size_t o0 = xbase0 + s * 32; if (o0 > TOT_X - 4) o0 = TOT_X - 4;
    size_t o1 = xbase1 + s * 32; if (o1 > TOT_X - 4) o1 = TOT_X - 4;
    v0 = *reinterpret_cast<const float4*>(x + o0);
    v1 = *reinterpret_cast<const float4*>(x + o1);
  };
  auto STORE = [&](int b) {
    *reinterpret_cast<bf16x8*>(&Al[b][ak][ach * 8]) = na;
    bf16x4 p0 = { (__bf16)v0.x, (__bf16)v0.y, (__bf16)v0.z, (__bf16)v0.w };
    bf16x4 p1 = { (__bf16)v1.x, (__bf16)v1.y, (__bf16)v1.z, (__bf16)v1.w };
    *reinterpret_cast<bf16x4*>(&Xl[b][xc][xch * 4])      = p0;
    *reinterpret_cast<bf16x4*>(&Xl[b][xc + 32][xch * 4]) = p1;
  };

  LOAD(0); STORE(0);
  LGKM_BAR();

  #pragma unroll 2
  for (int s = 0; s < 29; ++s) {
    if (s < 28) LOAD(s + 1);
    bf16x8 b = *reinterpret_cast<const bf16x8*>(&Xl[s & 1][16 * w + l15][lh * 8]);
    #pragma unroll
    for (int m = 0; m < 4; ++m) {
      bf16x8 a = *reinterpret_cast<const bf16x8*>(&Al[s & 1][16 * m + l15][lh * 8]);
      acc[m] = __builtin_amdgcn_mfma_f32_16x16x32_bf16(a, b, acc[m], 0, 0, 0);
    }
    if (s < 28) STORE((s + 1) & 1);
    LGKM_BAR();
  }

  const int c = c0 + 16 * w + l15;
  #pragma unroll
  for (int m = 0; m < 4; ++m) {
    #pragma unroll
    for (int r = 0; r < 4; ++r) {
      const int k = 16 * m + lh * 4 + r;
      out[((size_t)n * K_ + k) * C_ + c] =
          acc[m][r] - asum[n * K_ + k] * cent[(size_t)k * C_ + c];
    }
  }
}

extern "C" void kernel_launch(void* const* d_in, const int* in_sizes, int n_in,
                              void* d_out, int out_size, void* d_ws, size_t ws_size,
                              hipStream_t stream) {
  const float* x    = (const float*)d_in[0];
  const float* w    = (const float*)d_in[1];
  const float* cent = (const float*)d_in[2];
  float* out = (float*)d_out;
  char* wsb  = (char*)d_ws;
  __bf16* at   = (__bf16*)wsb;
  float*  asum = (float*)(wsb + ASUM_OFF);
  __bf16* wbr  = (__bf16*)(wsb + WBR_OFF);
  float*  ssqq = (float*)(wsb + SSQ_OFF);
  __bf16* Lq   = (__bf16*)(wsb + LQ_OFF);

  k_prep_w<<<dim3(16), dim3(256), 0, stream>>>(w, wbr, asum);
  k_phase1<<<dim3(256), dim3(512), 0, stream>>>(x, wbr, Lq, ssqq);
  k_softmax<<<dim3(15, 64), dim3(256), 0, stream>>>(Lq, ssqq, at, asum);
  k_phase2<<<dim3(8, 64), dim3(256), 0, stream>>>(x, at, asum, cent, out);
}

// Round 13
// 91.707 us; speedup vs baseline: 1.5342x; 1.5342x over previous
//
#include <hip/hip_runtime.h>
#include <stdint.h>

typedef __attribute__((ext_vector_type(8))) __bf16 bf16x8;
typedef __attribute__((ext_vector_type(4))) __bf16 bf16x4;
typedef __attribute__((ext_vector_type(4))) float f32x4;

// barrier WITHOUT vmcnt drain: LDS ops must land, global loads stay in flight
#define LGKM_BAR() do { asm volatile("s_waitcnt lgkmcnt(0)" ::: "memory"); \
                        __builtin_amdgcn_s_barrier(); } while (0)

namespace {
constexpr int N_ = 64, C_ = 512, P_ = 900, K_ = 64;
constexpr int PP = 960;                               // padded P for at
constexpr size_t TOT_X = (size_t)N_ * C_ * P_;        // 117,964,800 floats
constexpr size_t AT_BYTES = (size_t)N_ * K_ * PP * 2;         // bf16 a' [n][k][960]
constexpr size_t ASUM_OFF = AT_BYTES;                         // f32 [n][k]
constexpr size_t WB_OFF   = ASUM_OFF + (size_t)N_ * K_ * 4;   // bf16 w [k][c]
constexpr size_t SSQ_OFF  = WB_OFF + (size_t)K_ * C_ * 2 + 64;// f32 gssq [n][960]
}

// --- prep: w f32 [K][C] -> bf16 [K][C]; zero asum and gssq
__global__ __launch_bounds__(256) void k_prep_w(const float* __restrict__ w,
                                                __bf16* __restrict__ wb,
                                                float* __restrict__ asum,
                                                float* __restrict__ gssq) {
  const int t = blockIdx.x * 256 + threadIdx.x;      // 0..8191
  const int i = t * 4;
  if (i < K_ * C_) {
    float4 v = *reinterpret_cast<const float4*>(w + i);
    wb[i]   = (__bf16)v.x; wb[i+1] = (__bf16)v.y;
    wb[i+2] = (__bf16)v.z; wb[i+3] = (__bf16)v.w;
  }
  if (t < N_ * K_) asum[t] = 0.f;
  #pragma unroll
  for (int j = 0; j < 8; ++j) {
    const int idx = t * 8 + j;
    if (idx < N_ * PP) gssq[idx] = 0.f;
  }
}

// --- ssq + L3 warm-up: pure streaming read of x (m13 pattern: coalesced 1KB/wave,
//     no barriers, high TLP). block (cc, n) reads rows cc*64..cc*64+64 sequentially.
__global__ __launch_bounds__(256) void k_ssq(const float* __restrict__ x,
                                             float* __restrict__ gssq) {
  const int cc = blockIdx.x, n = blockIdx.y;
  const int tid = threadIdx.x;
  if (tid >= 225) return;                           // 225 f4-columns of 900
  const float* xb = x + ((size_t)n * C_ + cc * 64) * P_ + tid * 4;
  float4 sq = make_float4(0.f, 0.f, 0.f, 0.f);
  #pragma unroll 8
  for (int c = 0; c < 64; ++c) {
    const float4 v = *reinterpret_cast<const float4*>(xb + (size_t)c * P_);
    sq.x = fmaf(v.x, v.x, sq.x); sq.y = fmaf(v.y, v.y, sq.y);
    sq.z = fmaf(v.z, v.z, sq.z); sq.w = fmaf(v.w, v.w, sq.w);
  }
  float* o = gssq + (size_t)n * PP + tid * 4;
  unsafeAtomicAdd(o + 0, sq.x); unsafeAtomicAdd(o + 1, sq.y);
  unsafeAtomicAdd(o + 2, sq.z); unsafeAtomicAdd(o + 3, sq.w);
}

// --- phase 1 (R6 structure, ssq removed, x now L3-warm):
//     4-deep register prefetch ring; lgkm-only barriers; W rows preloaded to VGPR.
__global__ __launch_bounds__(256) void k_phase1(const float* __restrict__ x,
                                                const __bf16* __restrict__ wb,
                                                const float* __restrict__ gssq,
                                                __bf16* __restrict__ at,
                                                float* __restrict__ asum) {
  __shared__ __bf16 Xl[2][64][40];   // [buf][p][c32+pad]
  __shared__ float Sw[64][5];
  const int n   = blockIdx.y;
  const int p0  = blockIdx.x * 64;
  const int tid = threadIdx.x;
  const int w   = tid >> 6, l = tid & 63;
  const int l15 = l & 15,  lh = l >> 4;

  // preload A fragments (w rows) for all 16 K-steps
  bf16x8 afr[16];
  #pragma unroll
  for (int s = 0; s < 16; ++s)
    afr[s] = *reinterpret_cast<const bf16x8*>(
        wb + (size_t)(16 * w + l15) * C_ + s * 32 + lh * 8);

  const size_t xbase = (size_t)n * C_ * P_ + p0 + l;   // p = p0 + l
  float nx[4][8];                     // 4-deep prefetch ring
  f32x4 acc[4] = {};                  // frag t: p=p0+16t+l15, k=16w+lh*4+r

  #pragma unroll
  for (int b = 0; b < 4; ++b)
    #pragma unroll
    for (int j = 0; j < 8; ++j) {
      size_t off = xbase + (size_t)(b * 32 + w * 8 + j) * P_;
      if (off > TOT_X - 1) off = TOT_X - 1;
      nx[b][j] = x[off];
    }
  {
    bf16x8 pk;
    #pragma unroll
    for (int j = 0; j < 8; ++j) pk[j] = (__bf16)nx[0][j];
    *reinterpret_cast<bf16x8*>(&Xl[0][l][w * 8]) = pk;
  }
  LGKM_BAR();

  #pragma unroll
  for (int s = 0; s < 16; ++s) {
    if (s + 4 < 16) {
      #pragma unroll
      for (int j = 0; j < 8; ++j) {
        size_t off = xbase + (size_t)((s + 4) * 32 + w * 8 + j) * P_;
        if (off > TOT_X - 1) off = TOT_X - 1;
        nx[s & 3][j] = x[off];
      }
    }
    #pragma unroll
    for (int t = 0; t < 4; ++t) {
      bf16x8 b = *reinterpret_cast<const bf16x8*>(&Xl[s & 1][16 * t + l15][lh * 8]);
      acc[t] = __builtin_amdgcn_mfma_f32_16x16x32_bf16(afr[s], b, acc[t], 0, 0, 0);
    }
    if (s < 15) {
      bf16x8 pk;
      #pragma unroll
      for (int j = 0; j < 8; ++j) pk[j] = (__bf16)nx[(s + 1) & 3][j];
      *reinterpret_cast<bf16x8*>(&Xl[(s + 1) & 1][l][w * 8]) = pk;
      LGKM_BAR();
    }
  }

  float invn[4], invs_[4];
  bool valid[4];
  #pragma unroll
  for (int t = 0; t < 4; ++t) {
    const int pl = 16 * t + l15;
    valid[t] = (p0 + pl) < P_;
    const float ss = valid[t] ? gssq[(size_t)n * PP + p0 + pl] : 0.f;
    invn[t] = valid[t] ? (1.f / fmaxf(sqrtf(ss), 1e-12f)) : 0.f;
    float ps = 0.f;
    #pragma unroll
    for (int r = 0; r < 4; ++r) {
      acc[t][r] = __expf(acc[t][r] * invn[t]);   // maxless: |logit| <= ~0.5
      ps += acc[t][r];
    }
    ps += __shfl_xor(ps, 16, 64);
    ps += __shfl_xor(ps, 32, 64);
    if (lh == 0) Sw[pl][w] = ps;
  }
  __syncthreads();
  #pragma unroll
  for (int t = 0; t < 4; ++t) {
    const int pl = 16 * t + l15;
    invs_[t] = 1.f / (Sw[pl][0] + Sw[pl][1] + Sw[pl][2] + Sw[pl][3]);
  }

  #pragma unroll
  for (int t = 0; t < 4; ++t) {
    const int p = p0 + 16 * t + l15;
    #pragma unroll
    for (int r = 0; r < 4; ++r) {
      const int k = 16 * w + lh * 4 + r;
      const float ar = acc[t][r] * invs_[t];
      at[((size_t)n * K_ + k) * PP + p] = valid[t] ? (__bf16)(ar * invn[t]) : (__bf16)0.f;
    }
  }
  #pragma unroll
  for (int r = 0; r < 4; ++r) {
    float v = 0.f;
    #pragma unroll
    for (int t = 0; t < 4; ++t)
      v += valid[t] ? acc[t][r] * invs_[t] : 0.f;
    v += __shfl_xor(v, 1, 64); v += __shfl_xor(v, 2, 64);
    v += __shfl_xor(v, 4, 64); v += __shfl_xor(v, 8, 64);
    if (l15 == 0)
      unsafeAtomicAdd(asum + n * K_ + 16 * w + lh * 4 + r, v);
  }
}

// --- phase 2 (unchanged): vlad[k][c] = sum_p a'[k][p]*x[c][p] - asum[k]*cent[k][c]
__global__ __launch_bounds__(256) void k_phase2(const float* __restrict__ x,
                                                const __bf16* __restrict__ at,
                                                const float* __restrict__ asum,
                                                const float* __restrict__ cent,
                                                float* __restrict__ out) {
  __shared__ __bf16 Al[2][64][40];
  __shared__ __bf16 Xl[2][64][40];
  const int n   = blockIdx.y;
  const int c0  = blockIdx.x * 64;
  const int tid = threadIdx.x;
  const int w   = tid >> 6, l = tid & 63;
  const int l15 = l & 15,  lh = l >> 4;

  const int ak  = tid >> 2, ach = tid & 3;
  const int xc  = tid >> 3, xch = tid & 7;
  const size_t abase  = ((size_t)n * K_ + ak) * PP + ach * 8;
  const size_t xbase0 = ((size_t)n * C_ + c0 + xc) * P_ + xch * 4;
  const size_t xbase1 = ((size_t)n * C_ + c0 + xc + 32) * P_ + xch * 4;

  f32x4 acc[4] = {};
  bf16x8 na; float4 v0, v1;

  auto LOAD = [&](int s) {
    na = *reinterpret_cast<const bf16x8*>(at + abase + s * 32);
    size_t o0 = xbase0 + s * 32; if (o0 > TOT_X - 4) o0 = TOT_X - 4;
    size_t o1 = xbase1 + s * 32; if (o1 > TOT_X - 4) o1 = TOT_X - 4;
    v0 = *reinterpret_cast<const float4*>(x + o0);
    v1 = *reinterpret_cast<const float4*>(x + o1);
  };
  auto STORE = [&](int b) {
    *reinterpret_cast<bf16x8*>(&Al[b][ak][ach * 8]) = na;
    bf16x4 p0 = { (__bf16)v0.x, (__bf16)v0.y, (__bf16)v0.z, (__bf16)v0.w };
    bf16x4 p1 = { (__bf16)v1.x, (__bf16)v1.y, (__bf16)v1.z, (__bf16)v1.w };
    *reinterpret_cast<bf16x4*>(&Xl[b][xc][xch * 4])      = p0;
    *reinterpret_cast<bf16x4*>(&Xl[b][xc + 32][xch * 4]) = p1;
  };

  LOAD(0); STORE(0);
  LGKM_BAR();

  #pragma unroll 2
  for (int s = 0; s < 29; ++s) {
    if (s < 28) LOAD(s + 1);
    bf16x8 b = *reinterpret_cast<const bf16x8*>(&Xl[s & 1][16 * w + l15][lh * 8]);
    #pragma unroll
    for (int m = 0; m < 4; ++m) {
      bf16x8 a = *reinterpret_cast<const bf16x8*>(&Al[s & 1][16 * m + l15][lh * 8]);
      acc[m] = __builtin_amdgcn_mfma_f32_16x16x32_bf16(a, b, acc[m], 0, 0, 0);
    }
    if (s < 28) STORE((s + 1) & 1);
    LGKM_BAR();
  }

  const int c = c0 + 16 * w + l15;
  #pragma unroll
  for (int m = 0; m < 4; ++m) {
    #pragma unroll
    for (int r = 0; r < 4; ++r) {
      const int k = 16 * m + lh * 4 + r;
      out[((size_t)n * K_ + k) * C_ + c] =
          acc[m][r] - asum[n * K_ + k] * cent[(size_t)k * C_ + c];
    }
  }
}

extern "C" void kernel_launch(void* const* d_in, const int* in_sizes, int n_in,
                              void* d_out, int out_size, void* d_ws, size_t ws_size,
                              hipStream_t stream) {
  const float* x    = (const float*)d_in[0];
  const float* w    = (const float*)d_in[1];
  const float* cent = (const float*)d_in[2];
  float* out = (float*)d_out;
  char* wsb  = (char*)d_ws;
  __bf16* at   = (__bf16*)wsb;
  float*  asum = (float*)(wsb + ASUM_OFF);
  __bf16* wb   = (__bf16*)(wsb + WB_OFF);
  float*  gssq = (float*)(wsb + SSQ_OFF);

  k_prep_w<<<dim3(32), dim3(256), 0, stream>>>(w, wb, asum, gssq);
  k_ssq<<<dim3(8, 64), dim3(256), 0, stream>>>(x, gssq);
  k_phase1<<<dim3(15, 64), dim3(256), 0, stream>>>(x, wb, gssq, at, asum);
  k_phase2<<<dim3(8, 64), dim3(256), 0, stream>>>(x, at, asum, cent, out);
}

// Round 14
// 75.848 us; speedup vs baseline: 1.8549x; 1.2091x over previous
//
#include <hip/hip_runtime.h>
#include <stdint.h>

typedef __attribute__((ext_vector_type(8))) __bf16 bf16x8;
typedef __attribute__((ext_vector_type(4))) __bf16 bf16x4;
typedef __attribute__((ext_vector_type(4))) float f32x4;

// barrier WITHOUT vmcnt drain: LDS ops must land, global loads stay in flight
#define LGKM_BAR() do { asm volatile("s_waitcnt lgkmcnt(0)" ::: "memory"); \
                        __builtin_amdgcn_s_barrier(); } while (0)

namespace {
constexpr int N_ = 64, C_ = 512, P_ = 900, K_ = 64;
constexpr int PP = 960;                               // padded P for at
constexpr size_t TOT_X = (size_t)N_ * C_ * P_;        // 117,964,800 floats
constexpr size_t AT_BYTES = (size_t)N_ * K_ * PP * 2;         // bf16 a' [n][k][960]
constexpr size_t ASUM_OFF = AT_BYTES;                         // f32 [n][k]
constexpr size_t WB_OFF   = ASUM_OFF + (size_t)N_ * K_ * 4;   // bf16 w [k][c]
}

// --- prep: w f32 [K][C] -> bf16 [K][C]; zero asum
__global__ __launch_bounds__(256) void k_prep_w(const float* __restrict__ w,
                                                __bf16* __restrict__ wb,
                                                float* __restrict__ asum) {
  const int t = blockIdx.x * 256 + threadIdx.x;
  const int i = t * 4;
  if (i < K_ * C_) {
    float4 v = *reinterpret_cast<const float4*>(w + i);
    wb[i]   = (__bf16)v.x; wb[i+1] = (__bf16)v.y;
    wb[i+2] = (__bf16)v.z; wb[i+3] = (__bf16)v.w;
  }
  if (t < N_ * K_) asum[t] = 0.f;
}

// --- phase 1: R6 schedule (4-deep ring, lgkm-only barriers, afr in VGPRs,
//     in-wave softmax) with FLOAT4 staging loads (16B/lane) into R10's
//     conflict-free padded [c][66] LDS tile. Thread stages 2 c-rows x 4 p.
__global__ __launch_bounds__(256) void k_phase1(const float* __restrict__ x,
                                                const __bf16* __restrict__ wb,
                                                __bf16* __restrict__ at,
                                                float* __restrict__ asum) {
  __shared__ __bf16 Xl[2][32][66];   // [buf][c32][p64+pad] rows 132B
  __shared__ float ssq_l[64];
  __shared__ float Sw[64][5];
  const int n   = blockIdx.y;
  const int p0  = blockIdx.x * 64;
  const int tid = threadIdx.x;
  const int w   = tid >> 6, l = tid & 63;
  const int l15 = l & 15,  lh = l >> 4;

  // preload A fragments (w rows k=16w+l15) for all 16 K-steps: 64 VGPR
  bf16x8 afr[16];
  #pragma unroll
  for (int s = 0; s < 16; ++s)
    afr[s] = *reinterpret_cast<const bf16x8*>(
        wb + (size_t)(16 * w + l15) * C_ + s * 32 + lh * 8);

  if (tid < 64) ssq_l[tid] = 0.f;

  // staging map: thread owns c-rows {cl, cl+16} of each 32-c step, p-quad pq
  const int cl = tid >> 4;            // 0..15
  const int pq = (tid & 15) * 4;      // 0..60
  const size_t xrow = (size_t)n * C_ * P_ + p0 + pq;

  float4 ring[4][2];                  // 4-deep ring, 2 float4 per step
  float sq[4] = {0.f, 0.f, 0.f, 0.f};

  auto LOADR = [&](int s, int slot) {
    size_t o0 = xrow + (size_t)(s * 32 + cl) * P_;
    size_t o1 = xrow + (size_t)(s * 32 + cl + 16) * P_;
    if (o0 > TOT_X - 4) o0 = TOT_X - 4;
    if (o1 > TOT_X - 4) o1 = TOT_X - 4;
    ring[slot][0] = *reinterpret_cast<const float4*>(x + o0);
    ring[slot][1] = *reinterpret_cast<const float4*>(x + o1);
  };
  auto STORER = [&](int slot, int buf) {
    #pragma unroll
    for (int h = 0; h < 2; ++h) {
      const float4 v = ring[slot][h];
      sq[0] = fmaf(v.x, v.x, sq[0]); sq[1] = fmaf(v.y, v.y, sq[1]);
      sq[2] = fmaf(v.z, v.z, sq[2]); sq[3] = fmaf(v.w, v.w, sq[3]);
      bf16x4 o = { (__bf16)v.x, (__bf16)v.y, (__bf16)v.z, (__bf16)v.w };
      *reinterpret_cast<bf16x4*>(&Xl[buf][cl + h * 16][pq]) = o;
    }
  };

  // prologue: issue batches 0..3, store batch 0
  LOADR(0, 0); LOADR(1, 1); LOADR(2, 2); LOADR(3, 3);
  STORER(0, 0);
  LGKM_BAR();

  f32x4 acc[4] = {};                  // frag t: p=p0+16t+l15 -> col l15; k=16w+lh*4+r
  #pragma unroll
  for (int s = 0; s < 16; ++s) {
    if (s + 4 < 16) LOADR(s + 4, s & 3);
    #pragma unroll
    for (int t = 0; t < 4; ++t) {
      bf16x8 b;
      #pragma unroll
      for (int j = 0; j < 8; ++j) b[j] = Xl[s & 1][lh * 8 + j][t * 16 + l15];
      acc[t] = __builtin_amdgcn_mfma_f32_16x16x32_bf16(afr[s], b, acc[t], 0, 0, 0);
    }
    if (s < 15) {
      STORER((s + 1) & 3, (s + 1) & 1);
      LGKM_BAR();
    }
  }

  // ssq: per-thread 4-col partials -> LDS atomics -> per-p totals
  #pragma unroll
  for (int i = 0; i < 4; ++i) atomicAdd(&ssq_l[pq + i], sq[i]);
  __syncthreads();

  float invn[4], invs_[4];
  bool valid[4];
  #pragma unroll
  for (int t = 0; t < 4; ++t) {
    const int pl = 16 * t + l15;
    valid[t] = (p0 + pl) < P_;
    invn[t] = 1.f / fmaxf(sqrtf(ssq_l[pl]), 1e-12f);
    float ps = 0.f;
    #pragma unroll
    for (int r = 0; r < 4; ++r) {
      acc[t][r] = __expf(acc[t][r] * invn[t]);   // maxless: |logit| <= ~0.5
      ps += acc[t][r];
    }
    ps += __shfl_xor(ps, 16, 64);
    ps += __shfl_xor(ps, 32, 64);
    if (lh == 0) Sw[pl][w] = ps;
  }
  __syncthreads();
  #pragma unroll
  for (int t = 0; t < 4; ++t) {
    const int pl = 16 * t + l15;
    invs_[t] = 1.f / (Sw[pl][0] + Sw[pl][1] + Sw[pl][2] + Sw[pl][3]);
  }

  #pragma unroll
  for (int t = 0; t < 4; ++t) {
    const int p = p0 + 16 * t + l15;
    #pragma unroll
    for (int r = 0; r < 4; ++r) {
      const int k = 16 * w + lh * 4 + r;
      const float ar = acc[t][r] * invs_[t];
      at[((size_t)n * K_ + k) * PP + p] = valid[t] ? (__bf16)(ar * invn[t]) : (__bf16)0.f;
    }
  }
  #pragma unroll
  for (int r = 0; r < 4; ++r) {
    float v = 0.f;
    #pragma unroll
    for (int t = 0; t < 4; ++t)
      v += valid[t] ? acc[t][r] * invs_[t] : 0.f;
    v += __shfl_xor(v, 1, 64); v += __shfl_xor(v, 2, 64);
    v += __shfl_xor(v, 4, 64); v += __shfl_xor(v, 8, 64);
    if (l15 == 0)
      unsafeAtomicAdd(asum + n * K_ + 16 * w + lh * 4 + r, v);
  }
}

// --- phase 2 (unchanged): vlad[k][c] = sum_p a'[k][p]*x[c][p] - asum[k]*cent[k][c]
__global__ __launch_bounds__(256) void k_phase2(const float* __restrict__ x,
                                                const __bf16* __restrict__ at,
                                                const float* __restrict__ asum,
                                                const float* __restrict__ cent,
                                                float* __restrict__ out) {
  __shared__ __bf16 Al[2][64][40];
  __shared__ __bf16 Xl[2][64][40];
  const int n   = blockIdx.y;
  const int c0  = blockIdx.x * 64;
  const int tid = threadIdx.x;
  const int w   = tid >> 6, l = tid & 63;
  const int l15 = l & 15,  lh = l >> 4;

  const int ak  = tid >> 2, ach = tid & 3;
  const int xc  = tid >> 3, xch = tid & 7;
  const size_t abase  = ((size_t)n * K_ + ak) * PP + ach * 8;
  const size_t xbase0 = ((size_t)n * C_ + c0 + xc) * P_ + xch * 4;
  const size_t xbase1 = ((size_t)n * C_ + c0 + xc + 32) * P_ + xch * 4;

  f32x4 acc[4] = {};
  bf16x8 na; float4 v0, v1;

  auto LOAD = [&](int s) {
    na = *reinterpret_cast<const bf16x8*>(at + abase + s * 32);
    size_t o0 = xbase0 + s * 32; if (o0 > TOT_X - 4) o0 = TOT_X - 4;
    size_t o1 = xbase1 + s * 32; if (o1 > TOT_X - 4) o1 = TOT_X - 4;
    v0 = *reinterpret_cast<const float4*>(x + o0);
    v1 = *reinterpret_cast<const float4*>(x + o1);
  };
  auto STORE = [&](int b) {
    *reinterpret_cast<bf16x8*>(&Al[b][ak][ach * 8]) = na;
    bf16x4 p0 = { (__bf16)v0.x, (__bf16)v0.y, (__bf16)v0.z, (__bf16)v0.w };
    bf16x4 p1 = { (__bf16)v1.x, (__bf16)v1.y, (__bf16)v1.z, (__bf16)v1.w };
    *reinterpret_cast<bf16x4*>(&Xl[b][xc][xch * 4])      = p0;
    *reinterpret_cast<bf16x4*>(&Xl[b][xc + 32][xch * 4]) = p1;
  };

  LOAD(0); STORE(0);
  LGKM_BAR();

  #pragma unroll 2
  for (int s = 0; s < 29; ++s) {
    if (s < 28) LOAD(s + 1);
    bf16x8 b = *reinterpret_cast<const bf16x8*>(&Xl[s & 1][16 * w + l15][lh * 8]);
    #pragma unroll
    for (int m = 0; m < 4; ++m) {
      bf16x8 a = *reinterpret_cast<const bf16x8*>(&Al[s & 1][16 * m + l15][lh * 8]);
      acc[m] = __builtin_amdgcn_mfma_f32_16x16x32_bf16(a, b, acc[m], 0, 0, 0);
    }
    if (s < 28) STORE((s + 1) & 1);
    LGKM_BAR();
  }

  const int c = c0 + 16 * w + l15;
  #pragma unroll
  for (int m = 0; m < 4; ++m) {
    #pragma unroll
    for (int r = 0; r < 4; ++r) {
      const int k = 16 * m + lh * 4 + r;
      out[((size_t)n * K_ + k) * C_ + c] =
          acc[m][r] - asum[n * K_ + k] * cent[(size_t)k * C_ + c];
    }
  }
}

extern "C" void kernel_launch(void* const* d_in, const int* in_sizes, int n_in,
                              void* d_out, int out_size, void* d_ws, size_t ws_size,
                              hipStream_t stream) {
  const float* x    = (const float*)d_in[0];
  const float* w    = (const float*)d_in[1];
  const float* cent = (const float*)d_in[2];
  float* out = (float*)d_out;
  char* wsb  = (char*)d_ws;
  __bf16* at   = (__bf16*)wsb;
  float*  asum = (float*)(wsb + ASUM_OFF);
  __bf16* wb   = (__bf16*)(wsb + WB_OFF);

  k_prep_w<<<dim3(32), dim3(256), 0, stream>>>(w, wb, asum);
  k_phase1<<<dim3(15, 64), dim3(256), 0, stream>>>(x, wb, at, asum);
  k_phase2<<<dim3(8, 64), dim3(256), 0, stream>>>(x, at, asum, cent, out);
}